// Round 17
// baseline (479.855 us; speedup 1.0000x reference)
//
#include <hip/hip_runtime.h>
#include <math.h>

// Problem constants
constexpr int CVOC = 100;
constexpr int NCLS = 18;
constexpr int EE   = 512;   // word emb
constexpr int HHm  = 512;   // main GRU hidden
constexpr int CEc  = 128;   // char emb
constexpr int CHc  = 256;   // char GRU hidden
constexpr int BB   = 64;
constexpr int TT   = 64;
constexpr int CCh  = 16;    // chars per word
constexpr int NTOK = BB*TT;       // 4096
constexpr int G3C  = 3*CHc;       // 768
constexpr int G3H  = 3*HHm;       // 1536
constexpr int KIN  = EE + CHc;    // 768

typedef __attribute__((ext_vector_type(8))) short bf16x8;
typedef __attribute__((ext_vector_type(4))) float f32x4;

__device__ __forceinline__ float sigmoidf_(float x){ return 1.0f/(1.0f + __expf(-x)); }
__device__ __forceinline__ float tanhf_(float x){ return 1.0f - 2.0f/(__expf(2.0f*x) + 1.0f); }
__device__ __forceinline__ unsigned short f2bf(float x){
  unsigned int u = __float_as_uint(x);
  unsigned int r = (u + 0x7FFFu + ((u>>16)&1u)) >> 16;
  return (unsigned short)r;
}

// ---------------------------------------------------------------------------
// K1: char input-projection table, PADDED layout U2p[char][col][4]:
// slot = {r, z, n, pad}; biases folded (+bhh for r,z). One float4/word-col.
__global__ void k_uchar(const float* __restrict__ cemb, const float* __restrict__ wih,
                        const float* __restrict__ bih, const float* __restrict__ bhh,
                        float* __restrict__ U2p){
  const int c = blockIdx.x;        // char 0..99
  const int g = threadIdx.x;       // 0..767
  const float* a = cemb + (size_t)c*CEc;
  const float* w = wih  + (size_t)g*CEc;
  float s = 0.f;
  for(int k=0;k<CEc;k++) s = fmaf(a[k], w[k], s);
  s += bih[g];
  if(g < 2*CHc) s += bhh[g];
  const int gate = g >> 8;
  const int col  = g & 255;
  U2p[((size_t)c*256 + col)*4 + gate] = s;
}

// ---------------------------------------------------------------------------
// f32 -> bf16 (RNE)
__global__ void k_w2bf(const float* __restrict__ in, unsigned short* __restrict__ out,
                       int n){
  int i = blockIdx.x*256 + threadIdx.x;
  if(i < n) out[i] = f2bf(in[i]);
}

// ---------------------------------------------------------------------------
// K2 v9: char GRU, bf16 MFMA; U2 via coalesced float4 loads (unchanged).
__global__ __launch_bounds__(1024, 1) void k_chargru(
    const int* __restrict__ chars, const float* __restrict__ U2p,
    const unsigned short* __restrict__ Wb, const float* __restrict__ bhh,
    float* __restrict__ char_h){
  __shared__ unsigned short hb[16][280];   // 9KB bf16 h
  __shared__ int chs_all[16][16];          // 1KB [w][t]
  const int tid  = threadIdx.x;
  const int lane = tid & 63;
  const int wv   = tid >> 6;        // 0..15
  const int la   = lane & 15;
  const int lb   = lane >> 4;       // 0..3
  const int w0   = blockIdx.x * 16;
  const int c    = wv*16 + la;      // this thread's h-column (0..255)
  bf16x8 wreg[2][8];
  #pragma unroll
  for(int g=0; g<2; g++){
    const int gcol = g*CHc + c;
    #pragma unroll
    for(int ks=0; ks<8; ks++)
      wreg[g][ks] = *reinterpret_cast<const bf16x8*>(
          &Wb[(size_t)gcol*CHc + ks*32 + lb*8]);
  }
  const unsigned short* wnp = &Wb[(size_t)(2*CHc + c)*CHc + lb*8];  // n-gate row
  const float bhn = bhh[2*CHc + c];
  float hfr[4];
  #pragma unroll
  for(int i=0;i<4;i++) hfr[i]=0.f;
  for(int f=tid; f<16*280; f+=1024) (&hb[0][0])[f] = 0;
  if(tid < 256) chs_all[tid>>4][tid&15] = chars[(size_t)(w0 + (tid>>4))*CCh + (tid&15)];
  __syncthreads();

  for(int t=0; t<CCh; t++){
    float4 u2v[4];
    #pragma unroll
    for(int i=0;i<4;i++){
      const int ch = chs_all[lb*4 + i][t];
      u2v[i] = *reinterpret_cast<const float4*>(&U2p[(((size_t)ch*256) + c)*4]);
    }
    f32x4 acc[3];
    #pragma unroll
    for(int g=0;g<3;g++) acc[g] = (f32x4){0.f,0.f,0.f,0.f};
    {
      bf16x8 wn[4];
      #pragma unroll
      for(int q=0;q<4;q++)
        wn[q] = *reinterpret_cast<const bf16x8*>(wnp + q*32);
      #pragma unroll
      for(int ks=0; ks<4; ks++){
        bf16x8 a = *reinterpret_cast<const bf16x8*>(&hb[la][ks*32 + lb*8]);
        acc[0] = __builtin_amdgcn_mfma_f32_16x16x32_bf16(a, wreg[0][ks], acc[0], 0,0,0);
        acc[1] = __builtin_amdgcn_mfma_f32_16x16x32_bf16(a, wreg[1][ks], acc[1], 0,0,0);
        acc[2] = __builtin_amdgcn_mfma_f32_16x16x32_bf16(a, wn[ks],      acc[2], 0,0,0);
      }
      #pragma unroll
      for(int q=0;q<4;q++)
        wn[q] = *reinterpret_cast<const bf16x8*>(wnp + (4+q)*32);
      #pragma unroll
      for(int ks=4; ks<8; ks++){
        bf16x8 a = *reinterpret_cast<const bf16x8*>(&hb[la][ks*32 + lb*8]);
        acc[0] = __builtin_amdgcn_mfma_f32_16x16x32_bf16(a, wreg[0][ks], acc[0], 0,0,0);
        acc[1] = __builtin_amdgcn_mfma_f32_16x16x32_bf16(a, wreg[1][ks], acc[1], 0,0,0);
        acc[2] = __builtin_amdgcn_mfma_f32_16x16x32_bf16(a, wn[ks-4],    acc[2], 0,0,0);
      }
    }
    __syncthreads();
    #pragma unroll
    for(int i=0;i<4;i++){
      const int w = lb*4 + i;
      float r = sigmoidf_(u2v[i].x + acc[0][i]);
      float z = sigmoidf_(u2v[i].y + acc[1][i]);
      float n = tanhf_   (u2v[i].z + r*(acc[2][i] + bhn));
      float hn = (1.f - z)*n + z*hfr[i];
      hfr[i] = hn;
      hb[w][c] = f2bf(hn);
    }
    __syncthreads();
  }
  #pragma unroll
  for(int i=0;i<4;i++){
    const int w = lb*4 + i;
    char_h[(size_t)(w0+w)*CHc + c] = hfr[i];
  }
}

// ---------------------------------------------------------------------------
// K3a: pack A = [concat(wemb[x[tok]], chh[tok])] -> bf16 [4096][768]
__global__ __launch_bounds__(256) void k_abf(
    const int* __restrict__ x, const float* __restrict__ wemb,
    const float* __restrict__ chh, unsigned short* __restrict__ Abf){
  const int tok = blockIdx.x;
  const int tid = threadIdx.x;
  const int wid = x[tok];
  #pragma unroll
  for(int i=0;i<3;i++){
    int k = i*256 + tid;
    float v = (k < EE) ? wemb[(size_t)wid*EE + k] : chh[(size_t)tok*CHc + (k-EE)];
    Abf[(size_t)tok*KIN + k] = f2bf(v);
  }
}

// ---------------------------------------------------------------------------
// K3b: gx GEMM via bf16 MFMA (unchanged).
__global__ __launch_bounds__(256) void k_gxmfma(
    const unsigned short* __restrict__ Abf, const unsigned short* __restrict__ Wbih,
    const float* __restrict__ bih, const float* __restrict__ bhh,
    float* __restrict__ gx){
  __shared__ unsigned short As[64][136];   // 17.4KB
  const int tid  = threadIdx.x;
  const int lane = tid & 63;
  const int wv   = tid >> 6;        // 0..3
  const int la   = lane & 15;
  const int lb   = lane >> 4;       // 0..3
  const int rb   = blockIdx.x * 64;
  const int nb   = blockIdx.y * 64;
  const int g    = nb + wv*16 + la;
  f32x4 acc[4];
  #pragma unroll
  for(int mt=0;mt<4;mt++) acc[mt] = (f32x4){0.f,0.f,0.f,0.f};
  for(int kc=0; kc<6; kc++){
    #pragma unroll
    for(int i=0;i<4;i++){
      int idx = i*256 + tid;
      int row = idx >> 4, ck = idx & 15;
      *reinterpret_cast<uint4*>(&As[row][ck*8]) =
          *reinterpret_cast<const uint4*>(&Abf[(size_t)(rb+row)*KIN + kc*128 + ck*8]);
    }
    __syncthreads();
    #pragma unroll
    for(int ks=0; ks<4; ks++){
      bf16x8 b = *reinterpret_cast<const bf16x8*>(
          &Wbih[(size_t)g*KIN + kc*128 + ks*32 + lb*8]);
      #pragma unroll
      for(int mt=0;mt<4;mt++){
        bf16x8 a = *reinterpret_cast<const bf16x8*>(&As[mt*16 + la][ks*32 + lb*8]);
        acc[mt] = __builtin_amdgcn_mfma_f32_16x16x32_bf16(a, b, acc[mt], 0,0,0);
      }
    }
    __syncthreads();
  }
  const float bias = bih[g] + (g < 2*HHm ? bhh[g] : 0.f);
  #pragma unroll
  for(int mt=0;mt<4;mt++)
    #pragma unroll
    for(int i=0;i<4;i++){
      int row = rb + mt*16 + lb*4 + i;
      gx[(size_t)row*G3H + g] = acc[mt][i] + bias;
    }
}

// ---------------------------------------------------------------------------
// K4 v9: main GRU, tag-packed exchange, XCD-local swizzle, HALVED coupling.
// 128 blocks x 1024 thr = (jb 16) x (bb 8): block owns 32 j x 8 rows.
// Coupled producer set per batch-slice: 16 (was 32); polls/thread: 4 (was 8);
// per-thread dot unchanged (16k x 8 rows x 3 gates; wreg 48 VGPR); 16 waves/CU.
// Thread dot role: jp = lane&31, bq = lane>>5, kw = tid>>6 -> k-chunk
// [kw*32 + bq*16, +16) for j = jb*32+jp, rows 0..7.
// Reduce: shfl lane^32 (bq pair) -> red[3][8][32][17] -> finalize tid<256.
__global__ __launch_bounds__(1024, 1) void k_grumain(
    const float* __restrict__ Whh, const float* __restrict__ gx,
    const float* __restrict__ bhh, float* __restrict__ outh,
    unsigned long long* __restrict__ hx){
  __shared__ float hsh[8][516];        // 16.5KB
  __shared__ float red[3][8][32][17];  // 52.2KB [g][b][jp][kw]
  const int tid  = threadIdx.x;
  const int lane = tid & 63;
  const int kw   = tid >> 6;           // 0..15
  const int jp   = lane & 31;
  const int bq   = lane >> 5;          // 0..1
  const int jb   = blockIdx.x >> 3;    // 0..15
  const int bb   = blockIdx.x & 7;     // XCD-local batch slice
  const int jglob = jb*32 + jp;
  const int kbase = kw*32 + bq*16;
  float4 wreg[3][4];
  #pragma unroll
  for(int g=0; g<3; g++)
    #pragma unroll
    for(int q=0; q<4; q++)
      wreg[g][q] = *reinterpret_cast<const float4*>(
          &Whh[((size_t)g*HHm + jglob)*HHm + kbase + q*4]);
  // finalize mapping (tid<256): fb = tid>>5 (row), fj = tid&31 (j)
  const int fb  = tid >> 5;
  const int fj  = tid & 31;
  const int fjg = jb*32 + fj;
  const int fbg = bb*8 + fb;
  const float fbhn = bhh[2*HHm + fjg];

  for(int t=0; t<TT; t++){
    float gxr=0.f, gxz=0.f, gxn=0.f;
    if(tid < 256){
      const size_t tok = (size_t)fbg*TT + t;
      gxr = gx[tok*G3H +           fjg];
      gxz = gx[tok*G3H + HHm +     fjg];
      gxn = gx[tok*G3H + 2*HHm +   fjg];
    }
    if(t > 0){
      const unsigned int want = (unsigned int)t;
      const size_t sbase = (size_t)((t-1)&1)*BB*HHm;
      // poll 8 rows x 512 j = 4096 u64 over 1024 threads: 4 each (issue-then-check)
      const unsigned long long* p[4];
      unsigned long long v[4];
      #pragma unroll
      for(int i=0;i<4;i++){
        int f = i*1024 + tid;
        int b = f >> 9, k = f & 511;
        p[i] = &hx[sbase + (size_t)(bb*8+b)*HHm + k];
        v[i] = __hip_atomic_load(p[i], __ATOMIC_RELAXED, __HIP_MEMORY_SCOPE_AGENT);
      }
      #pragma unroll
      for(int i=0;i<4;i++){
        while((unsigned int)(v[i]>>32) != want){
          __builtin_amdgcn_s_sleep(1);
          v[i] = __hip_atomic_load(p[i], __ATOMIC_RELAXED, __HIP_MEMORY_SCOPE_AGENT);
        }
        int f = i*1024 + tid;
        int b = f >> 9, k = f & 511;
        hsh[b][k] = __uint_as_float((unsigned int)v[i]);
      }
      __syncthreads();
      float aR[8], aZ[8], aN[8];
      #pragma unroll
      for(int b=0;b<8;b++){ aR[b]=0.f; aZ[b]=0.f; aN[b]=0.f; }
      #pragma unroll
      for(int b=0; b<8; b++){
        float4 h0 = *reinterpret_cast<const float4*>(&hsh[b][kbase+0]);
        float4 h1 = *reinterpret_cast<const float4*>(&hsh[b][kbase+4]);
        float4 h2 = *reinterpret_cast<const float4*>(&hsh[b][kbase+8]);
        float4 h3 = *reinterpret_cast<const float4*>(&hsh[b][kbase+12]);
        aR[b] = fmaf(h0.x,wreg[0][0].x, fmaf(h0.y,wreg[0][0].y, fmaf(h0.z,wreg[0][0].z, fmaf(h0.w,wreg[0][0].w, aR[b]))));
        aR[b] = fmaf(h1.x,wreg[0][1].x, fmaf(h1.y,wreg[0][1].y, fmaf(h1.z,wreg[0][1].z, fmaf(h1.w,wreg[0][1].w, aR[b]))));
        aR[b] = fmaf(h2.x,wreg[0][2].x, fmaf(h2.y,wreg[0][2].y, fmaf(h2.z,wreg[0][2].z, fmaf(h2.w,wreg[0][2].w, aR[b]))));
        aR[b] = fmaf(h3.x,wreg[0][3].x, fmaf(h3.y,wreg[0][3].y, fmaf(h3.z,wreg[0][3].z, fmaf(h3.w,wreg[0][3].w, aR[b]))));
        aZ[b] = fmaf(h0.x,wreg[1][0].x, fmaf(h0.y,wreg[1][0].y, fmaf(h0.z,wreg[1][0].z, fmaf(h0.w,wreg[1][0].w, aZ[b]))));
        aZ[b] = fmaf(h1.x,wreg[1][1].x, fmaf(h1.y,wreg[1][1].y, fmaf(h1.z,wreg[1][1].z, fmaf(h1.w,wreg[1][1].w, aZ[b]))));
        aZ[b] = fmaf(h2.x,wreg[1][2].x, fmaf(h2.y,wreg[1][2].y, fmaf(h2.z,wreg[1][2].z, fmaf(h2.w,wreg[1][2].w, aZ[b]))));
        aZ[b] = fmaf(h3.x,wreg[1][3].x, fmaf(h3.y,wreg[1][3].y, fmaf(h3.z,wreg[1][3].z, fmaf(h3.w,wreg[1][3].w, aZ[b]))));
        aN[b] = fmaf(h0.x,wreg[2][0].x, fmaf(h0.y,wreg[2][0].y, fmaf(h0.z,wreg[2][0].z, fmaf(h0.w,wreg[2][0].w, aN[b]))));
        aN[b] = fmaf(h1.x,wreg[2][1].x, fmaf(h1.y,wreg[2][1].y, fmaf(h1.z,wreg[2][1].z, fmaf(h1.w,wreg[2][1].w, aN[b]))));
        aN[b] = fmaf(h2.x,wreg[2][2].x, fmaf(h2.y,wreg[2][2].y, fmaf(h2.z,wreg[2][2].z, fmaf(h2.w,wreg[2][2].w, aN[b]))));
        aN[b] = fmaf(h3.x,wreg[2][3].x, fmaf(h3.y,wreg[2][3].y, fmaf(h3.z,wreg[2][3].z, fmaf(h3.w,wreg[2][3].w, aN[b]))));
      }
      // bq-pair reduce (lane ^ 32), then bq=0 lanes write partials
      #pragma unroll
      for(int b=0;b<8;b++){
        aR[b] += __shfl_xor(aR[b], 32, 64);
        aZ[b] += __shfl_xor(aZ[b], 32, 64);
        aN[b] += __shfl_xor(aN[b], 32, 64);
      }
      if(bq == 0){
        #pragma unroll
        for(int b=0;b<8;b++){
          red[0][b][jp][kw] = aR[b];
          red[1][b][jp][kw] = aZ[b];
          red[2][b][jp][kw] = aN[b];
        }
      }
      __syncthreads();
    }
    if(tid < 256){
      float sR=0.f, sZ=0.f, sN=0.f, hold=0.f;
      if(t > 0){
        #pragma unroll
        for(int w=0; w<16; w++){
          sR += red[0][fb][fj][w];
          sZ += red[1][fb][fj][w];
          sN += red[2][fb][fj][w];
        }
        hold = hsh[fb][fjg];
      }
      float rg = sigmoidf_(gxr + sR);
      float zg = sigmoidf_(gxz + sZ);
      float ng = tanhf_   (gxn + rg*(sN + fbhn));
      float hnew = (1.f - zg)*ng + zg*hold;
      outh[((size_t)t*BB + fbg)*HHm + fjg] = hnew;   // f32 for k_cls
      unsigned long long pv = ((unsigned long long)(unsigned int)(t+1) << 32)
                              | (unsigned long long)__float_as_uint(hnew);
      __hip_atomic_store(&hx[(size_t)(t&1)*BB*HHm + (size_t)fbg*HHm + fjg], pv,
                         __ATOMIC_RELAXED, __HIP_MEMORY_SCOPE_AGENT);
    }
    __syncthreads();
  }
}

// ---------------------------------------------------------------------------
// K5: classifier. One block per time-step t; reads outh[t][b][j].
__global__ __launch_bounds__(256) void k_cls(
    const float* __restrict__ outh, const float* __restrict__ clsW,
    const float* __restrict__ clsb, float* __restrict__ out){
  __shared__ float wls[20*HHm];     // 40KB
  __shared__ float hch[64][129];    // 33KB
  const int tid = threadIdx.x;
  const int t = blockIdx.x;
  const int b = tid & 63;
  const int q = tid >> 6;
  const int c0 = q*5;
  for(int f = tid*4; f < 20*HHm; f += 1024){
    float4 v = make_float4(0.f,0.f,0.f,0.f);
    if(f < NCLS*HHm) v = *reinterpret_cast<const float4*>(&clsW[f]);
    *reinterpret_cast<float4*>(&wls[f]) = v;
  }
  float acc[5] = {0.f,0.f,0.f,0.f,0.f};
  for(int kc=0; kc<4; kc++){
    __syncthreads();
    for(int i=0;i<32;i++){
      int f = i*256 + tid;
      int b2 = f >> 7, kk = f & 127;
      hch[b2][kk] = outh[((size_t)t*BB + b2)*HHm + kc*128 + kk];
    }
    __syncthreads();
    for(int k=0;k<128;k++){
      float hv = hch[b][k];
      #pragma unroll
      for(int i=0;i<5;i++)
        acc[i] = fmaf(hv, wls[(size_t)(c0+i)*HHm + kc*128 + k], acc[i]);
    }
  }
  #pragma unroll
  for(int i=0;i<5;i++){
    int cls = c0 + i;
    if(cls < NCLS) out[((size_t)b*TT + t)*NCLS + cls] = acc[i] + clsb[cls];
  }
}

// ---------------------------------------------------------------------------
extern "C" void kernel_launch(void* const* d_in, const int* in_sizes, int n_in,
                              void* d_out, int out_size, void* d_ws, size_t ws_size,
                              hipStream_t stream){
  const int*   x     = (const int*)d_in[0];
  const int*   chars = (const int*)d_in[1];
  const float* wemb  = (const float*)d_in[2];
  const float* cemb  = (const float*)d_in[3];
  const float* cWih  = (const float*)d_in[4];
  const float* cWhh  = (const float*)d_in[5];
  const float* cbih  = (const float*)d_in[6];
  const float* cbhh  = (const float*)d_in[7];
  const float* gWih  = (const float*)d_in[8];
  const float* gWhh  = (const float*)d_in[9];
  const float* gbih  = (const float*)d_in[10];
  const float* gbhh  = (const float*)d_in[11];
  const float* clsW  = (const float*)d_in[12];
  const float* clsb  = (const float*)d_in[13];
  float* out = (float*)d_out;
  float* ws  = (float*)d_ws;

  // workspace layout (floats unless noted)
  float* U2p   = ws;                   // 100*256*4  = 102400
  float* chh   = U2p + 102400;         // 4096*256   = 1048576
  float* gx    = chh + 1048576;        // 4096*1536  = 6291456   [token][g]
  float* outh  = gx + 6291456;         // 64*64*512  = 2097152   [t][b][j]
  unsigned long long* hx = (unsigned long long*)(outh + 2097152); // 2*64*512 u64
  unsigned short* Wb   = (unsigned short*)(hx + 2*BB*HHm);  // 768*256 bf16 (char Whh)
  unsigned short* Wbih = Wb + G3C*CHc;                      // 1536*768 bf16 (gWih)
  unsigned short* Abf  = (unsigned short*)outh;             // alias: used only pre-grumain

  k_uchar<<<CVOC, G3C, 0, stream>>>(cemb, cWih, cbih, cbhh, U2p);
  k_w2bf<<<(G3C*CHc + 255)/256, 256, 0, stream>>>(cWhh, Wb, G3C*CHc);
  k_w2bf<<<(G3H*KIN + 255)/256, 256, 0, stream>>>(gWih, Wbih, G3H*KIN);
  k_chargru<<<NTOK/16, 1024, 0, stream>>>(chars, U2p, Wb, cbhh, chh);
  k_abf<<<NTOK, 256, 0, stream>>>(x, wemb, chh, Abf);
  k_gxmfma<<<dim3(NTOK/64, G3H/64), 256, 0, stream>>>(Abf, Wbih, gbih, gbhh, gx);
  k_grumain<<<128, 1024, 0, stream>>>(gWhh, gx, gbhh, outh, hx);
  k_cls<<<TT, 256, 0, stream>>>(outh, clsW, clsb, out);
}

// Round 18
// 446.034 us; speedup vs baseline: 1.0758x; 1.0758x over previous
//
#include <hip/hip_runtime.h>
#include <math.h>

// Problem constants
constexpr int CVOC = 100;
constexpr int NCLS = 18;
constexpr int EE   = 512;   // word emb
constexpr int HHm  = 512;   // main GRU hidden
constexpr int CEc  = 128;   // char emb
constexpr int CHc  = 256;   // char GRU hidden
constexpr int BB   = 64;
constexpr int TT   = 64;
constexpr int CCh  = 16;    // chars per word
constexpr int NTOK = BB*TT;       // 4096
constexpr int G3C  = 3*CHc;       // 768
constexpr int G3H  = 3*HHm;       // 1536
constexpr int KIN  = EE + CHc;    // 768

typedef __attribute__((ext_vector_type(8))) short bf16x8;
typedef __attribute__((ext_vector_type(4))) float f32x4;

__device__ __forceinline__ float sigmoidf_(float x){ return 1.0f/(1.0f + __expf(-x)); }
__device__ __forceinline__ float tanhf_(float x){ return 1.0f - 2.0f/(__expf(2.0f*x) + 1.0f); }
__device__ __forceinline__ unsigned short f2bf(float x){
  unsigned int u = __float_as_uint(x);
  unsigned int r = (u + 0x7FFFu + ((u>>16)&1u)) >> 16;
  return (unsigned short)r;
}

// ---------------------------------------------------------------------------
// K1: char input-projection table, PADDED layout U2p[char][col][4]:
// slot = {r, z, n, pad}; biases folded (+bhh for r,z). One float4/word-col.
__global__ void k_uchar(const float* __restrict__ cemb, const float* __restrict__ wih,
                        const float* __restrict__ bih, const float* __restrict__ bhh,
                        float* __restrict__ U2p){
  const int c = blockIdx.x;        // char 0..99
  const int g = threadIdx.x;       // 0..767
  const float* a = cemb + (size_t)c*CEc;
  const float* w = wih  + (size_t)g*CEc;
  float s = 0.f;
  for(int k=0;k<CEc;k++) s = fmaf(a[k], w[k], s);
  s += bih[g];
  if(g < 2*CHc) s += bhh[g];
  const int gate = g >> 8;
  const int col  = g & 255;
  U2p[((size_t)c*256 + col)*4 + gate] = s;
}

// ---------------------------------------------------------------------------
// f32 -> bf16 (RNE)
__global__ void k_w2bf(const float* __restrict__ in, unsigned short* __restrict__ out,
                       int n){
  int i = blockIdx.x*256 + threadIdx.x;
  if(i < n) out[i] = f2bf(in[i]);
}

// ---------------------------------------------------------------------------
// K2 v9: char GRU, bf16 MFMA; U2 via coalesced float4 loads (round-16 code).
__global__ __launch_bounds__(1024, 1) void k_chargru(
    const int* __restrict__ chars, const float* __restrict__ U2p,
    const unsigned short* __restrict__ Wb, const float* __restrict__ bhh,
    float* __restrict__ char_h){
  __shared__ unsigned short hb[16][280];   // 9KB bf16 h
  __shared__ int chs_all[16][16];          // 1KB [w][t]
  const int tid  = threadIdx.x;
  const int lane = tid & 63;
  const int wv   = tid >> 6;        // 0..15
  const int la   = lane & 15;
  const int lb   = lane >> 4;       // 0..3
  const int w0   = blockIdx.x * 16;
  const int c    = wv*16 + la;      // this thread's h-column (0..255)
  bf16x8 wreg[2][8];
  #pragma unroll
  for(int g=0; g<2; g++){
    const int gcol = g*CHc + c;
    #pragma unroll
    for(int ks=0; ks<8; ks++)
      wreg[g][ks] = *reinterpret_cast<const bf16x8*>(
          &Wb[(size_t)gcol*CHc + ks*32 + lb*8]);
  }
  const unsigned short* wnp = &Wb[(size_t)(2*CHc + c)*CHc + lb*8];  // n-gate row
  const float bhn = bhh[2*CHc + c];
  float hfr[4];
  #pragma unroll
  for(int i=0;i<4;i++) hfr[i]=0.f;
  for(int f=tid; f<16*280; f+=1024) (&hb[0][0])[f] = 0;
  if(tid < 256) chs_all[tid>>4][tid&15] = chars[(size_t)(w0 + (tid>>4))*CCh + (tid&15)];
  __syncthreads();

  for(int t=0; t<CCh; t++){
    float4 u2v[4];
    #pragma unroll
    for(int i=0;i<4;i++){
      const int ch = chs_all[lb*4 + i][t];
      u2v[i] = *reinterpret_cast<const float4*>(&U2p[(((size_t)ch*256) + c)*4]);
    }
    f32x4 acc[3];
    #pragma unroll
    for(int g=0;g<3;g++) acc[g] = (f32x4){0.f,0.f,0.f,0.f};
    {
      bf16x8 wn[4];
      #pragma unroll
      for(int q=0;q<4;q++)
        wn[q] = *reinterpret_cast<const bf16x8*>(wnp + q*32);
      #pragma unroll
      for(int ks=0; ks<4; ks++){
        bf16x8 a = *reinterpret_cast<const bf16x8*>(&hb[la][ks*32 + lb*8]);
        acc[0] = __builtin_amdgcn_mfma_f32_16x16x32_bf16(a, wreg[0][ks], acc[0], 0,0,0);
        acc[1] = __builtin_amdgcn_mfma_f32_16x16x32_bf16(a, wreg[1][ks], acc[1], 0,0,0);
        acc[2] = __builtin_amdgcn_mfma_f32_16x16x32_bf16(a, wn[ks],      acc[2], 0,0,0);
      }
      #pragma unroll
      for(int q=0;q<4;q++)
        wn[q] = *reinterpret_cast<const bf16x8*>(wnp + (4+q)*32);
      #pragma unroll
      for(int ks=4; ks<8; ks++){
        bf16x8 a = *reinterpret_cast<const bf16x8*>(&hb[la][ks*32 + lb*8]);
        acc[0] = __builtin_amdgcn_mfma_f32_16x16x32_bf16(a, wreg[0][ks], acc[0], 0,0,0);
        acc[1] = __builtin_amdgcn_mfma_f32_16x16x32_bf16(a, wreg[1][ks], acc[1], 0,0,0);
        acc[2] = __builtin_amdgcn_mfma_f32_16x16x32_bf16(a, wn[ks-4],    acc[2], 0,0,0);
      }
    }
    __syncthreads();
    #pragma unroll
    for(int i=0;i<4;i++){
      const int w = lb*4 + i;
      float r = sigmoidf_(u2v[i].x + acc[0][i]);
      float z = sigmoidf_(u2v[i].y + acc[1][i]);
      float n = tanhf_   (u2v[i].z + r*(acc[2][i] + bhn));
      float hn = (1.f - z)*n + z*hfr[i];
      hfr[i] = hn;
      hb[w][c] = f2bf(hn);
    }
    __syncthreads();
  }
  #pragma unroll
  for(int i=0;i<4;i++){
    const int w = lb*4 + i;
    char_h[(size_t)(w0+w)*CHc + c] = hfr[i];
  }
}

// ---------------------------------------------------------------------------
// K3: gx GEMM via bf16 MFMA, FUSED gather+pack (no Abf round-trip).
// A-tile staged directly from wemb[x[row]] / chh[row] with in-register f2bf.
// Chunks of 8 never straddle the 512-boundary (both 8-aligned). M=4096 N=1536
// K=768, 64x64 tiles, 4 waves. bias folded (+bhh for r,z). Output f32 gx.
__global__ __launch_bounds__(256) void k_gxmfma(
    const int* __restrict__ x, const float* __restrict__ wemb,
    const float* __restrict__ chh, const unsigned short* __restrict__ Wbih,
    const float* __restrict__ bih, const float* __restrict__ bhh,
    float* __restrict__ gx){
  __shared__ unsigned short As[64][136];   // 17.4KB
  __shared__ int xs[64];
  const int tid  = threadIdx.x;
  const int lane = tid & 63;
  const int wv   = tid >> 6;        // 0..3
  const int la   = lane & 15;
  const int lb   = lane >> 4;       // 0..3
  const int rb   = blockIdx.x * 64;
  const int nb   = blockIdx.y * 64;
  const int g    = nb + wv*16 + la;
  if(tid < 64) xs[tid] = x[rb + tid];
  f32x4 acc[4];
  #pragma unroll
  for(int mt=0;mt<4;mt++) acc[mt] = (f32x4){0.f,0.f,0.f,0.f};
  __syncthreads();
  for(int kc=0; kc<6; kc++){
    // stage As[64][128] bf16: gather f32 -> cvt -> LDS
    #pragma unroll
    for(int i=0;i<4;i++){
      int idx = i*256 + tid;
      int row = idx >> 4, ck = idx & 15;
      int k = kc*128 + ck*8;
      const float* src = (k < EE) ? &wemb[(size_t)xs[row]*EE + k]
                                  : &chh[(size_t)(rb+row)*CHc + (k - EE)];
      float4 v0 = *reinterpret_cast<const float4*>(src);
      float4 v1 = *reinterpret_cast<const float4*>(src + 4);
      unsigned short tmp[8];
      tmp[0]=f2bf(v0.x); tmp[1]=f2bf(v0.y); tmp[2]=f2bf(v0.z); tmp[3]=f2bf(v0.w);
      tmp[4]=f2bf(v1.x); tmp[5]=f2bf(v1.y); tmp[6]=f2bf(v1.z); tmp[7]=f2bf(v1.w);
      *reinterpret_cast<uint4*>(&As[row][ck*8]) = *reinterpret_cast<const uint4*>(tmp);
    }
    __syncthreads();
    #pragma unroll
    for(int ks=0; ks<4; ks++){
      bf16x8 b = *reinterpret_cast<const bf16x8*>(
          &Wbih[(size_t)g*KIN + kc*128 + ks*32 + lb*8]);
      #pragma unroll
      for(int mt=0;mt<4;mt++){
        bf16x8 a = *reinterpret_cast<const bf16x8*>(&As[mt*16 + la][ks*32 + lb*8]);
        acc[mt] = __builtin_amdgcn_mfma_f32_16x16x32_bf16(a, b, acc[mt], 0,0,0);
      }
    }
    __syncthreads();
  }
  const float bias = bih[g] + (g < 2*HHm ? bhh[g] : 0.f);
  #pragma unroll
  for(int mt=0;mt<4;mt++)
    #pragma unroll
    for(int i=0;i<4;i++){
      int row = rb + mt*16 + lb*4 + i;
      gx[(size_t)row*G3H + g] = acc[mt][i] + bias;
    }
}

// ---------------------------------------------------------------------------
// K4 v6x: main GRU, tag-packed h exchange + pipelined poll + XCD-local
// swizzle (round-16 code, measured 334us). 256 blocks x 512 thr.
__global__ __launch_bounds__(512) void k_grumain(
    const float* __restrict__ Whh, const float* __restrict__ gx,
    const float* __restrict__ bhh, float* __restrict__ outh,
    unsigned long long* __restrict__ hx){
  __shared__ float hsh[8][516];      // 16.5KB
  __shared__ float red[3][8][16][9]; // 13.8KB
  const int tid  = threadIdx.x;
  const int lane = tid & 63;
  const int kw   = tid >> 6;
  const int jp   = lane & 15;
  const int bq   = lane >> 4;
  const int jb   = blockIdx.x >> 3;   // 0..31
  const int bb   = blockIdx.x & 7;    // XCD-local batch slice
  const int jglob = jb*16 + jp;
  const int kbase = kw*64 + bq*16;
  float4 wreg[3][4];
  #pragma unroll
  for(int g=0; g<3; g++)
    #pragma unroll
    for(int q=0; q<4; q++)
      wreg[g][q] = *reinterpret_cast<const float4*>(
          &Whh[((size_t)g*HHm + jglob)*HHm + kbase + q*4]);
  const int fb  = tid >> 4;
  const int fj  = tid & 15;
  const int fjg = jb*16 + fj;
  const int fbg = bb*8 + fb;
  const float fbhn = bhh[2*HHm + fjg];

  for(int t=0; t<TT; t++){
    float gxr=0.f, gxz=0.f, gxn=0.f;
    if(tid < 128){
      const size_t tok = (size_t)fbg*TT + t;
      gxr = gx[tok*G3H +           fjg];
      gxz = gx[tok*G3H + HHm +     fjg];
      gxn = gx[tok*G3H + 2*HHm +   fjg];
    }
    if(t > 0){
      const unsigned int want = (unsigned int)t;
      const size_t sbase = (size_t)((t-1)&1)*BB*HHm;
      const unsigned long long* p[8];
      unsigned long long v[8];
      #pragma unroll
      for(int i=0;i<8;i++){
        int f = i*512 + tid;
        int b = f >> 9, k = f & 511;
        p[i] = &hx[sbase + (size_t)(bb*8+b)*HHm + k];
        v[i] = __hip_atomic_load(p[i], __ATOMIC_RELAXED, __HIP_MEMORY_SCOPE_AGENT);
      }
      #pragma unroll
      for(int i=0;i<8;i++){
        while((unsigned int)(v[i]>>32) != want){
          __builtin_amdgcn_s_sleep(1);
          v[i] = __hip_atomic_load(p[i], __ATOMIC_RELAXED, __HIP_MEMORY_SCOPE_AGENT);
        }
        int f = i*512 + tid;
        int b = f >> 9, k = f & 511;
        hsh[b][k] = __uint_as_float((unsigned int)v[i]);
      }
      __syncthreads();
      float aR[8], aZ[8], aN[8];
      #pragma unroll
      for(int b=0;b<8;b++){ aR[b]=0.f; aZ[b]=0.f; aN[b]=0.f; }
      #pragma unroll
      for(int b=0; b<8; b++){
        float4 h0 = *reinterpret_cast<const float4*>(&hsh[b][kbase+0]);
        float4 h1 = *reinterpret_cast<const float4*>(&hsh[b][kbase+4]);
        float4 h2 = *reinterpret_cast<const float4*>(&hsh[b][kbase+8]);
        float4 h3 = *reinterpret_cast<const float4*>(&hsh[b][kbase+12]);
        aR[b] = fmaf(h0.x,wreg[0][0].x, fmaf(h0.y,wreg[0][0].y, fmaf(h0.z,wreg[0][0].z, fmaf(h0.w,wreg[0][0].w, aR[b]))));
        aR[b] = fmaf(h1.x,wreg[0][1].x, fmaf(h1.y,wreg[0][1].y, fmaf(h1.z,wreg[0][1].z, fmaf(h1.w,wreg[0][1].w, aR[b]))));
        aR[b] = fmaf(h2.x,wreg[0][2].x, fmaf(h2.y,wreg[0][2].y, fmaf(h2.z,wreg[0][2].z, fmaf(h2.w,wreg[0][2].w, aR[b]))));
        aR[b] = fmaf(h3.x,wreg[0][3].x, fmaf(h3.y,wreg[0][3].y, fmaf(h3.z,wreg[0][3].z, fmaf(h3.w,wreg[0][3].w, aR[b]))));
        aZ[b] = fmaf(h0.x,wreg[1][0].x, fmaf(h0.y,wreg[1][0].y, fmaf(h0.z,wreg[1][0].z, fmaf(h0.w,wreg[1][0].w, aZ[b]))));
        aZ[b] = fmaf(h1.x,wreg[1][1].x, fmaf(h1.y,wreg[1][1].y, fmaf(h1.z,wreg[1][1].z, fmaf(h1.w,wreg[1][1].w, aZ[b]))));
        aZ[b] = fmaf(h2.x,wreg[1][2].x, fmaf(h2.y,wreg[1][2].y, fmaf(h2.z,wreg[1][2].z, fmaf(h2.w,wreg[1][2].w, aZ[b]))));
        aZ[b] = fmaf(h3.x,wreg[1][3].x, fmaf(h3.y,wreg[1][3].y, fmaf(h3.z,wreg[1][3].z, fmaf(h3.w,wreg[1][3].w, aZ[b]))));
        aN[b] = fmaf(h0.x,wreg[2][0].x, fmaf(h0.y,wreg[2][0].y, fmaf(h0.z,wreg[2][0].z, fmaf(h0.w,wreg[2][0].w, aN[b]))));
        aN[b] = fmaf(h1.x,wreg[2][1].x, fmaf(h1.y,wreg[2][1].y, fmaf(h1.z,wreg[2][1].z, fmaf(h1.w,wreg[2][1].w, aN[b]))));
        aN[b] = fmaf(h2.x,wreg[2][2].x, fmaf(h2.y,wreg[2][2].y, fmaf(h2.z,wreg[2][2].z, fmaf(h2.w,wreg[2][2].w, aN[b]))));
        aN[b] = fmaf(h3.x,wreg[2][3].x, fmaf(h3.y,wreg[2][3].y, fmaf(h3.z,wreg[2][3].z, fmaf(h3.w,wreg[2][3].w, aN[b]))));
      }
      #pragma unroll
      for(int b=0;b<8;b++){
        aR[b] += __shfl_xor(aR[b], 16, 64); aR[b] += __shfl_xor(aR[b], 32, 64);
        aZ[b] += __shfl_xor(aZ[b], 16, 64); aZ[b] += __shfl_xor(aZ[b], 32, 64);
        aN[b] += __shfl_xor(aN[b], 16, 64); aN[b] += __shfl_xor(aN[b], 32, 64);
      }
      #pragma unroll
      for(int i=0;i<2;i++){
        int b = bq*2 + i;
        red[0][b][jp][kw] = aR[b];
        red[1][b][jp][kw] = aZ[b];
        red[2][b][jp][kw] = aN[b];
      }
      __syncthreads();
    }
    if(tid < 128){
      float sR=0.f, sZ=0.f, sN=0.f, hold=0.f;
      if(t > 0){
        #pragma unroll
        for(int w=0; w<8; w++){
          sR += red[0][fb][fj][w];
          sZ += red[1][fb][fj][w];
          sN += red[2][fb][fj][w];
        }
        hold = hsh[fb][fjg];
      }
      float rg = sigmoidf_(gxr + sR);
      float zg = sigmoidf_(gxz + sZ);
      float ng = tanhf_   (gxn + rg*(sN + fbhn));
      float hnew = (1.f - zg)*ng + zg*hold;
      outh[((size_t)t*BB + fbg)*HHm + fjg] = hnew;   // f32 for k_cls
      unsigned long long pv = ((unsigned long long)(unsigned int)(t+1) << 32)
                              | (unsigned long long)__float_as_uint(hnew);
      __hip_atomic_store(&hx[(size_t)(t&1)*BB*HHm + (size_t)fbg*HHm + fjg], pv,
                         __ATOMIC_RELAXED, __HIP_MEMORY_SCOPE_AGENT);
    }
    __syncthreads();
  }
}

// ---------------------------------------------------------------------------
// K5: classifier. One block per time-step t; reads outh[t][b][j].
__global__ __launch_bounds__(256) void k_cls(
    const float* __restrict__ outh, const float* __restrict__ clsW,
    const float* __restrict__ clsb, float* __restrict__ out){
  __shared__ float wls[20*HHm];     // 40KB
  __shared__ float hch[64][129];    // 33KB
  const int tid = threadIdx.x;
  const int t = blockIdx.x;
  const int b = tid & 63;
  const int q = tid >> 6;
  const int c0 = q*5;
  for(int f = tid*4; f < 20*HHm; f += 1024){
    float4 v = make_float4(0.f,0.f,0.f,0.f);
    if(f < NCLS*HHm) v = *reinterpret_cast<const float4*>(&clsW[f]);
    *reinterpret_cast<float4*>(&wls[f]) = v;
  }
  float acc[5] = {0.f,0.f,0.f,0.f,0.f};
  for(int kc=0; kc<4; kc++){
    __syncthreads();
    for(int i=0;i<32;i++){
      int f = i*256 + tid;
      int b2 = f >> 7, kk = f & 127;
      hch[b2][kk] = outh[((size_t)t*BB + b2)*HHm + kc*128 + kk];
    }
    __syncthreads();
    for(int k=0;k<128;k++){
      float hv = hch[b][k];
      #pragma unroll
      for(int i=0;i<5;i++)
        acc[i] = fmaf(hv, wls[(size_t)(c0+i)*HHm + kc*128 + k], acc[i]);
    }
  }
  #pragma unroll
  for(int i=0;i<5;i++){
    int cls = c0 + i;
    if(cls < NCLS) out[((size_t)b*TT + t)*NCLS + cls] = acc[i] + clsb[cls];
  }
}

// ---------------------------------------------------------------------------
extern "C" void kernel_launch(void* const* d_in, const int* in_sizes, int n_in,
                              void* d_out, int out_size, void* d_ws, size_t ws_size,
                              hipStream_t stream){
  const int*   x     = (const int*)d_in[0];
  const int*   chars = (const int*)d_in[1];
  const float* wemb  = (const float*)d_in[2];
  const float* cemb  = (const float*)d_in[3];
  const float* cWih  = (const float*)d_in[4];
  const float* cWhh  = (const float*)d_in[5];
  const float* cbih  = (const float*)d_in[6];
  const float* cbhh  = (const float*)d_in[7];
  const float* gWih  = (const float*)d_in[8];
  const float* gWhh  = (const float*)d_in[9];
  const float* gbih  = (const float*)d_in[10];
  const float* gbhh  = (const float*)d_in[11];
  const float* clsW  = (const float*)d_in[12];
  const float* clsb  = (const float*)d_in[13];
  float* out = (float*)d_out;
  float* ws  = (float*)d_ws;

  // workspace layout (floats unless noted)
  float* U2p   = ws;                   // 100*256*4  = 102400
  float* chh   = U2p + 102400;         // 4096*256   = 1048576
  float* gx    = chh + 1048576;        // 4096*1536  = 6291456   [token][g]
  float* outh  = gx + 6291456;         // 64*64*512  = 2097152   [t][b][j]
  unsigned long long* hx = (unsigned long long*)(outh + 2097152); // 2*64*512 u64
  unsigned short* Wb   = (unsigned short*)(hx + 2*BB*HHm);  // 768*256 bf16 (char Whh)
  unsigned short* Wbih = Wb + G3C*CHc;                      // 1536*768 bf16 (gWih)

  k_uchar<<<CVOC, G3C, 0, stream>>>(cemb, cWih, cbih, cbhh, U2p);
  k_w2bf<<<(G3C*CHc + 255)/256, 256, 0, stream>>>(cWhh, Wb, G3C*CHc);
  k_w2bf<<<(G3H*KIN + 255)/256, 256, 0, stream>>>(gWih, Wbih, G3H*KIN);
  k_chargru<<<NTOK/16, 1024, 0, stream>>>(chars, U2p, Wb, cbhh, chh);
  k_gxmfma<<<dim3(NTOK/64, G3H/64), 256, 0, stream>>>(x, wemb, chh, Wbih, gbih, gbhh, gx);
  k_grumain<<<256, 512, 0, stream>>>(gWhh, gx, gbhh, outh, hx);
  k_cls<<<TT, 256, 0, stream>>>(outh, clsW, clsb, out);
}

// Round 19
// 419.708 us; speedup vs baseline: 1.1433x; 1.0627x over previous
//
#include <hip/hip_runtime.h>
#include <math.h>

// Problem constants
constexpr int CVOC = 100;
constexpr int NCLS = 18;
constexpr int EE   = 512;   // word emb
constexpr int HHm  = 512;   // main GRU hidden
constexpr int CEc  = 128;   // char emb
constexpr int CHc  = 256;   // char GRU hidden
constexpr int BB   = 64;
constexpr int TT   = 64;
constexpr int CCh  = 16;    // chars per word
constexpr int NTOK = BB*TT;       // 4096
constexpr int G3C  = 3*CHc;       // 768
constexpr int G3H  = 3*HHm;       // 1536
constexpr int KIN  = EE + CHc;    // 768

typedef __attribute__((ext_vector_type(8))) short bf16x8;
typedef __attribute__((ext_vector_type(4))) float f32x4;

__device__ __forceinline__ float sigmoidf_(float x){ return 1.0f/(1.0f + __expf(-x)); }
__device__ __forceinline__ float tanhf_(float x){ return 1.0f - 2.0f/(__expf(2.0f*x) + 1.0f); }
__device__ __forceinline__ unsigned short f2bf(float x){
  unsigned int u = __float_as_uint(x);
  unsigned int r = (u + 0x7FFFu + ((u>>16)&1u)) >> 16;
  return (unsigned short)r;
}

// ---------------------------------------------------------------------------
// K1: char input-projection table, PADDED layout U2p[char][col][4]:
// slot = {r, z, n, pad}; biases folded (+bhh for r,z). One float4/word-col.
__global__ void k_uchar(const float* __restrict__ cemb, const float* __restrict__ wih,
                        const float* __restrict__ bih, const float* __restrict__ bhh,
                        float* __restrict__ U2p){
  const int c = blockIdx.x;        // char 0..99
  const int g = threadIdx.x;       // 0..767
  const float* a = cemb + (size_t)c*CEc;
  const float* w = wih  + (size_t)g*CEc;
  float s = 0.f;
  for(int k=0;k<CEc;k++) s = fmaf(a[k], w[k], s);
  s += bih[g];
  if(g < 2*CHc) s += bhh[g];
  const int gate = g >> 8;
  const int col  = g & 255;
  U2p[((size_t)c*256 + col)*4 + gate] = s;
}

// ---------------------------------------------------------------------------
// f32 -> bf16 (RNE)
__global__ void k_w2bf(const float* __restrict__ in, unsigned short* __restrict__ out,
                       int n){
  int i = blockIdx.x*256 + threadIdx.x;
  if(i < n) out[i] = f2bf(in[i]);
}

// ---------------------------------------------------------------------------
// K2 v9: char GRU, bf16 MFMA; U2 via coalesced float4 loads (round-16 code).
__global__ __launch_bounds__(1024, 1) void k_chargru(
    const int* __restrict__ chars, const float* __restrict__ U2p,
    const unsigned short* __restrict__ Wb, const float* __restrict__ bhh,
    float* __restrict__ char_h){
  __shared__ unsigned short hb[16][280];   // 9KB bf16 h
  __shared__ int chs_all[16][16];          // 1KB [w][t]
  const int tid  = threadIdx.x;
  const int lane = tid & 63;
  const int wv   = tid >> 6;        // 0..15
  const int la   = lane & 15;
  const int lb   = lane >> 4;       // 0..3
  const int w0   = blockIdx.x * 16;
  const int c    = wv*16 + la;      // this thread's h-column (0..255)
  bf16x8 wreg[2][8];
  #pragma unroll
  for(int g=0; g<2; g++){
    const int gcol = g*CHc + c;
    #pragma unroll
    for(int ks=0; ks<8; ks++)
      wreg[g][ks] = *reinterpret_cast<const bf16x8*>(
          &Wb[(size_t)gcol*CHc + ks*32 + lb*8]);
  }
  const unsigned short* wnp = &Wb[(size_t)(2*CHc + c)*CHc + lb*8];  // n-gate row
  const float bhn = bhh[2*CHc + c];
  float hfr[4];
  #pragma unroll
  for(int i=0;i<4;i++) hfr[i]=0.f;
  for(int f=tid; f<16*280; f+=1024) (&hb[0][0])[f] = 0;
  if(tid < 256) chs_all[tid>>4][tid&15] = chars[(size_t)(w0 + (tid>>4))*CCh + (tid&15)];
  __syncthreads();

  for(int t=0; t<CCh; t++){
    float4 u2v[4];
    #pragma unroll
    for(int i=0;i<4;i++){
      const int ch = chs_all[lb*4 + i][t];
      u2v[i] = *reinterpret_cast<const float4*>(&U2p[(((size_t)ch*256) + c)*4]);
    }
    f32x4 acc[3];
    #pragma unroll
    for(int g=0;g<3;g++) acc[g] = (f32x4){0.f,0.f,0.f,0.f};
    {
      bf16x8 wn[4];
      #pragma unroll
      for(int q=0;q<4;q++)
        wn[q] = *reinterpret_cast<const bf16x8*>(wnp + q*32);
      #pragma unroll
      for(int ks=0; ks<4; ks++){
        bf16x8 a = *reinterpret_cast<const bf16x8*>(&hb[la][ks*32 + lb*8]);
        acc[0] = __builtin_amdgcn_mfma_f32_16x16x32_bf16(a, wreg[0][ks], acc[0], 0,0,0);
        acc[1] = __builtin_amdgcn_mfma_f32_16x16x32_bf16(a, wreg[1][ks], acc[1], 0,0,0);
        acc[2] = __builtin_amdgcn_mfma_f32_16x16x32_bf16(a, wn[ks],      acc[2], 0,0,0);
      }
      #pragma unroll
      for(int q=0;q<4;q++)
        wn[q] = *reinterpret_cast<const bf16x8*>(wnp + (4+q)*32);
      #pragma unroll
      for(int ks=4; ks<8; ks++){
        bf16x8 a = *reinterpret_cast<const bf16x8*>(&hb[la][ks*32 + lb*8]);
        acc[0] = __builtin_amdgcn_mfma_f32_16x16x32_bf16(a, wreg[0][ks], acc[0], 0,0,0);
        acc[1] = __builtin_amdgcn_mfma_f32_16x16x32_bf16(a, wreg[1][ks], acc[1], 0,0,0);
        acc[2] = __builtin_amdgcn_mfma_f32_16x16x32_bf16(a, wn[ks-4],    acc[2], 0,0,0);
      }
    }
    __syncthreads();
    #pragma unroll
    for(int i=0;i<4;i++){
      const int w = lb*4 + i;
      float r = sigmoidf_(u2v[i].x + acc[0][i]);
      float z = sigmoidf_(u2v[i].y + acc[1][i]);
      float n = tanhf_   (u2v[i].z + r*(acc[2][i] + bhn));
      float hn = (1.f - z)*n + z*hfr[i];
      hfr[i] = hn;
      hb[w][c] = f2bf(hn);
    }
    __syncthreads();
  }
  #pragma unroll
  for(int i=0;i<4;i++){
    const int w = lb*4 + i;
    char_h[(size_t)(w0+w)*CHc + c] = hfr[i];
  }
}

// ---------------------------------------------------------------------------
// K3: gx GEMM via bf16 MFMA, FUSED gather+pack (round-18 code).
__global__ __launch_bounds__(256) void k_gxmfma(
    const int* __restrict__ x, const float* __restrict__ wemb,
    const float* __restrict__ chh, const unsigned short* __restrict__ Wbih,
    const float* __restrict__ bih, const float* __restrict__ bhh,
    float* __restrict__ gx){
  __shared__ unsigned short As[64][136];   // 17.4KB
  __shared__ int xs[64];
  const int tid  = threadIdx.x;
  const int lane = tid & 63;
  const int wv   = tid >> 6;        // 0..3
  const int la   = lane & 15;
  const int lb   = lane >> 4;       // 0..3
  const int rb   = blockIdx.x * 64;
  const int nb   = blockIdx.y * 64;
  const int g    = nb + wv*16 + la;
  if(tid < 64) xs[tid] = x[rb + tid];
  f32x4 acc[4];
  #pragma unroll
  for(int mt=0;mt<4;mt++) acc[mt] = (f32x4){0.f,0.f,0.f,0.f};
  __syncthreads();
  for(int kc=0; kc<6; kc++){
    #pragma unroll
    for(int i=0;i<4;i++){
      int idx = i*256 + tid;
      int row = idx >> 4, ck = idx & 15;
      int k = kc*128 + ck*8;
      const float* src = (k < EE) ? &wemb[(size_t)xs[row]*EE + k]
                                  : &chh[(size_t)(rb+row)*CHc + (k - EE)];
      float4 v0 = *reinterpret_cast<const float4*>(src);
      float4 v1 = *reinterpret_cast<const float4*>(src + 4);
      unsigned short tmp[8];
      tmp[0]=f2bf(v0.x); tmp[1]=f2bf(v0.y); tmp[2]=f2bf(v0.z); tmp[3]=f2bf(v0.w);
      tmp[4]=f2bf(v1.x); tmp[5]=f2bf(v1.y); tmp[6]=f2bf(v1.z); tmp[7]=f2bf(v1.w);
      *reinterpret_cast<uint4*>(&As[row][ck*8]) = *reinterpret_cast<const uint4*>(tmp);
    }
    __syncthreads();
    #pragma unroll
    for(int ks=0; ks<4; ks++){
      bf16x8 b = *reinterpret_cast<const bf16x8*>(
          &Wbih[(size_t)g*KIN + kc*128 + ks*32 + lb*8]);
      #pragma unroll
      for(int mt=0;mt<4;mt++){
        bf16x8 a = *reinterpret_cast<const bf16x8*>(&As[mt*16 + la][ks*32 + lb*8]);
        acc[mt] = __builtin_amdgcn_mfma_f32_16x16x32_bf16(a, b, acc[mt], 0,0,0);
      }
    }
    __syncthreads();
  }
  const float bias = bih[g] + (g < 2*HHm ? bhh[g] : 0.f);
  #pragma unroll
  for(int mt=0;mt<4;mt++)
    #pragma unroll
    for(int i=0;i<4;i++){
      int row = rb + mt*16 + lb*4 + i;
      gx[(size_t)row*G3H + g] = acc[mt][i] + bias;
    }
}

// ---------------------------------------------------------------------------
// K4 v10: main GRU, PACKED bf16-pair exchange + register-resident h_old.
// Structure = v6x (256 blocks x 512 thr, XCD-local bb = blockIdx&7), with:
//  (a) hold (z*h_old path) in a persistent f32 register hreg — finalize thread
//      for (b,j) is the same thread every step; NEVER read from exchange.
//  (b) hx u64 = {tag32 | bf16(h_{2k+1})<<16 | bf16(h_2k)}: 2 h per word ->
//      polls/thread 8->4, stores/block 128->64 (even lanes, shfl-paired).
//      Exchanged h feeds ONLY the matmul operand (bf16 ok, chargru precedent).
//  Stage converts bf16->f32 (exact shift) into hsh; dot loop unchanged.
__global__ __launch_bounds__(512) void k_grumain(
    const float* __restrict__ Whh, const float* __restrict__ gx,
    const float* __restrict__ bhh, float* __restrict__ outh,
    unsigned long long* __restrict__ hx){
  __shared__ float hsh[8][516];      // 16.5KB
  __shared__ float red[3][8][16][9]; // 13.8KB
  const int tid  = threadIdx.x;
  const int lane = tid & 63;
  const int kw   = tid >> 6;
  const int jp   = lane & 15;
  const int bq   = lane >> 4;
  const int jb   = blockIdx.x >> 3;   // 0..31
  const int bb   = blockIdx.x & 7;    // XCD-local batch slice
  const int jglob = jb*16 + jp;
  const int kbase = kw*64 + bq*16;
  float4 wreg[3][4];
  #pragma unroll
  for(int g=0; g<3; g++)
    #pragma unroll
    for(int q=0; q<4; q++)
      wreg[g][q] = *reinterpret_cast<const float4*>(
          &Whh[((size_t)g*HHm + jglob)*HHm + kbase + q*4]);
  const int fb  = tid >> 4;
  const int fj  = tid & 15;
  const int fjg = jb*16 + fj;
  const int fbg = bb*8 + fb;
  const float fbhn = bhh[2*HHm + fjg];
  float hreg = 0.f;                  // persistent f32 h_old (exact z-path)

  for(int t=0; t<TT; t++){
    float gxr=0.f, gxz=0.f, gxn=0.f;
    if(tid < 128){
      const size_t tok = (size_t)fbg*TT + t;
      gxr = gx[tok*G3H +           fjg];
      gxz = gx[tok*G3H + HHm +     fjg];
      gxn = gx[tok*G3H + 2*HHm +   fjg];
    }
    if(t > 0){
      const unsigned int want = (unsigned int)t;
      const size_t sbase = (size_t)((t-1)&1)*BB*(HHm/2);
      // poll 8 rows x 256 packed u64 = 2048 over 512 threads: 4 each
      const unsigned long long* p[4];
      unsigned long long v[4];
      #pragma unroll
      for(int i=0;i<4;i++){
        int f = i*512 + tid;
        int b = f >> 8, j2 = f & 255;
        p[i] = &hx[sbase + (size_t)(bb*8+b)*(HHm/2) + j2];
        v[i] = __hip_atomic_load(p[i], __ATOMIC_RELAXED, __HIP_MEMORY_SCOPE_AGENT);
      }
      #pragma unroll
      for(int i=0;i<4;i++){
        while((unsigned int)(v[i]>>32) != want){
          __builtin_amdgcn_s_sleep(1);
          v[i] = __hip_atomic_load(p[i], __ATOMIC_RELAXED, __HIP_MEMORY_SCOPE_AGENT);
        }
        int f = i*512 + tid;
        int b = f >> 8, j2 = f & 255;
        unsigned int lo = (unsigned int)v[i];
        hsh[b][j2*2+0] = __uint_as_float((lo & 0xFFFFu) << 16);
        hsh[b][j2*2+1] = __uint_as_float((lo & 0xFFFF0000u));
      }
      __syncthreads();
      float aR[8], aZ[8], aN[8];
      #pragma unroll
      for(int b=0;b<8;b++){ aR[b]=0.f; aZ[b]=0.f; aN[b]=0.f; }
      #pragma unroll
      for(int b=0; b<8; b++){
        float4 h0 = *reinterpret_cast<const float4*>(&hsh[b][kbase+0]);
        float4 h1 = *reinterpret_cast<const float4*>(&hsh[b][kbase+4]);
        float4 h2 = *reinterpret_cast<const float4*>(&hsh[b][kbase+8]);
        float4 h3 = *reinterpret_cast<const float4*>(&hsh[b][kbase+12]);
        aR[b] = fmaf(h0.x,wreg[0][0].x, fmaf(h0.y,wreg[0][0].y, fmaf(h0.z,wreg[0][0].z, fmaf(h0.w,wreg[0][0].w, aR[b]))));
        aR[b] = fmaf(h1.x,wreg[0][1].x, fmaf(h1.y,wreg[0][1].y, fmaf(h1.z,wreg[0][1].z, fmaf(h1.w,wreg[0][1].w, aR[b]))));
        aR[b] = fmaf(h2.x,wreg[0][2].x, fmaf(h2.y,wreg[0][2].y, fmaf(h2.z,wreg[0][2].z, fmaf(h2.w,wreg[0][2].w, aR[b]))));
        aR[b] = fmaf(h3.x,wreg[0][3].x, fmaf(h3.y,wreg[0][3].y, fmaf(h3.z,wreg[0][3].z, fmaf(h3.w,wreg[0][3].w, aR[b]))));
        aZ[b] = fmaf(h0.x,wreg[1][0].x, fmaf(h0.y,wreg[1][0].y, fmaf(h0.z,wreg[1][0].z, fmaf(h0.w,wreg[1][0].w, aZ[b]))));
        aZ[b] = fmaf(h1.x,wreg[1][1].x, fmaf(h1.y,wreg[1][1].y, fmaf(h1.z,wreg[1][1].z, fmaf(h1.w,wreg[1][1].w, aZ[b]))));
        aZ[b] = fmaf(h2.x,wreg[1][2].x, fmaf(h2.y,wreg[1][2].y, fmaf(h2.z,wreg[1][2].z, fmaf(h2.w,wreg[1][2].w, aZ[b]))));
        aZ[b] = fmaf(h3.x,wreg[1][3].x, fmaf(h3.y,wreg[1][3].y, fmaf(h3.z,wreg[1][3].z, fmaf(h3.w,wreg[1][3].w, aZ[b]))));
        aN[b] = fmaf(h0.x,wreg[2][0].x, fmaf(h0.y,wreg[2][0].y, fmaf(h0.z,wreg[2][0].z, fmaf(h0.w,wreg[2][0].w, aN[b]))));
        aN[b] = fmaf(h1.x,wreg[2][1].x, fmaf(h1.y,wreg[2][1].y, fmaf(h1.z,wreg[2][1].z, fmaf(h1.w,wreg[2][1].w, aN[b]))));
        aN[b] = fmaf(h2.x,wreg[2][2].x, fmaf(h2.y,wreg[2][2].y, fmaf(h2.z,wreg[2][2].z, fmaf(h2.w,wreg[2][2].w, aN[b]))));
        aN[b] = fmaf(h3.x,wreg[2][3].x, fmaf(h3.y,wreg[2][3].y, fmaf(h3.z,wreg[2][3].z, fmaf(h3.w,wreg[2][3].w, aN[b]))));
      }
      #pragma unroll
      for(int b=0;b<8;b++){
        aR[b] += __shfl_xor(aR[b], 16, 64); aR[b] += __shfl_xor(aR[b], 32, 64);
        aZ[b] += __shfl_xor(aZ[b], 16, 64); aZ[b] += __shfl_xor(aZ[b], 32, 64);
        aN[b] += __shfl_xor(aN[b], 16, 64); aN[b] += __shfl_xor(aN[b], 32, 64);
      }
      #pragma unroll
      for(int i=0;i<2;i++){
        int b = bq*2 + i;
        red[0][b][jp][kw] = aR[b];
        red[1][b][jp][kw] = aZ[b];
        red[2][b][jp][kw] = aN[b];
      }
      __syncthreads();
    }
    if(tid < 128){
      float sR=0.f, sZ=0.f, sN=0.f;
      if(t > 0){
        #pragma unroll
        for(int w=0; w<8; w++){
          sR += red[0][fb][fj][w];
          sZ += red[1][fb][fj][w];
          sN += red[2][fb][fj][w];
        }
      }
      float rg = sigmoidf_(gxr + sR);
      float zg = sigmoidf_(gxz + sZ);
      float ng = tanhf_   (gxn + rg*(sN + fbhn));
      float hnew = (1.f - zg)*ng + zg*hreg;     // exact f32 h_old
      hreg = hnew;
      outh[((size_t)t*BB + fbg)*HHm + fjg] = hnew;   // f32 for k_cls
      // pack pair (fj even: low16 = my h, high16 = fj-odd neighbor's h)
      unsigned int mybf = (unsigned int)f2bf(hnew);
      unsigned int nbbf = (unsigned int)__shfl_xor((int)mybf, 1, 64);
      if((fj & 1) == 0){
        unsigned int lo = mybf | (nbbf << 16);
        unsigned long long pv = ((unsigned long long)(unsigned int)(t+1) << 32)
                                | (unsigned long long)lo;
        __hip_atomic_store(&hx[(size_t)(t&1)*BB*(HHm/2) + (size_t)fbg*(HHm/2) + (fjg>>1)],
                           pv, __ATOMIC_RELAXED, __HIP_MEMORY_SCOPE_AGENT);
      }
    }
    __syncthreads();
  }
}

// ---------------------------------------------------------------------------
// K5: classifier. One block per time-step t; reads outh[t][b][j].
__global__ __launch_bounds__(256) void k_cls(
    const float* __restrict__ outh, const float* __restrict__ clsW,
    const float* __restrict__ clsb, float* __restrict__ out){
  __shared__ float wls[20*HHm];     // 40KB
  __shared__ float hch[64][129];    // 33KB
  const int tid = threadIdx.x;
  const int t = blockIdx.x;
  const int b = tid & 63;
  const int q = tid >> 6;
  const int c0 = q*5;
  for(int f = tid*4; f < 20*HHm; f += 1024){
    float4 v = make_float4(0.f,0.f,0.f,0.f);
    if(f < NCLS*HHm) v = *reinterpret_cast<const float4*>(&clsW[f]);
    *reinterpret_cast<float4*>(&wls[f]) = v;
  }
  float acc[5] = {0.f,0.f,0.f,0.f,0.f};
  for(int kc=0; kc<4; kc++){
    __syncthreads();
    for(int i=0;i<32;i++){
      int f = i*256 + tid;
      int b2 = f >> 7, kk = f & 127;
      hch[b2][kk] = outh[((size_t)t*BB + b2)*HHm + kc*128 + kk];
    }
    __syncthreads();
    for(int k=0;k<128;k++){
      float hv = hch[b][k];
      #pragma unroll
      for(int i=0;i<5;i++)
        acc[i] = fmaf(hv, wls[(size_t)(c0+i)*HHm + kc*128 + k], acc[i]);
    }
  }
  #pragma unroll
  for(int i=0;i<5;i++){
    int cls = c0 + i;
    if(cls < NCLS) out[((size_t)b*TT + t)*NCLS + cls] = acc[i] + clsb[cls];
  }
}

// ---------------------------------------------------------------------------
extern "C" void kernel_launch(void* const* d_in, const int* in_sizes, int n_in,
                              void* d_out, int out_size, void* d_ws, size_t ws_size,
                              hipStream_t stream){
  const int*   x     = (const int*)d_in[0];
  const int*   chars = (const int*)d_in[1];
  const float* wemb  = (const float*)d_in[2];
  const float* cemb  = (const float*)d_in[3];
  const float* cWih  = (const float*)d_in[4];
  const float* cWhh  = (const float*)d_in[5];
  const float* cbih  = (const float*)d_in[6];
  const float* cbhh  = (const float*)d_in[7];
  const float* gWih  = (const float*)d_in[8];
  const float* gWhh  = (const float*)d_in[9];
  const float* gbih  = (const float*)d_in[10];
  const float* gbhh  = (const float*)d_in[11];
  const float* clsW  = (const float*)d_in[12];
  const float* clsb  = (const float*)d_in[13];
  float* out = (float*)d_out;
  float* ws  = (float*)d_ws;

  // workspace layout (floats unless noted)
  float* U2p   = ws;                   // 100*256*4  = 102400
  float* chh   = U2p + 102400;         // 4096*256   = 1048576
  float* gx    = chh + 1048576;        // 4096*1536  = 6291456   [token][g]
  float* outh  = gx + 6291456;         // 64*64*512  = 2097152   [t][b][j]
  unsigned long long* hx = (unsigned long long*)(outh + 2097152); // 2*64*256 u64 (packed)
  unsigned short* Wb   = (unsigned short*)(hx + 2*BB*(HHm/2)); // 768*256 bf16 (char Whh)
  unsigned short* Wbih = Wb + G3C*CHc;                         // 1536*768 bf16 (gWih)

  k_uchar<<<CVOC, G3C, 0, stream>>>(cemb, cWih, cbih, cbhh, U2p);
  k_w2bf<<<(G3C*CHc + 255)/256, 256, 0, stream>>>(cWhh, Wb, G3C*CHc);
  k_w2bf<<<(G3H*KIN + 255)/256, 256, 0, stream>>>(gWih, Wbih, G3H*KIN);
  k_chargru<<<NTOK/16, 1024, 0, stream>>>(chars, U2p, Wb, cbhh, chh);
  k_gxmfma<<<dim3(NTOK/64, G3H/64), 256, 0, stream>>>(x, wemb, chh, Wbih, gbih, gbhh, gx);
  k_grumain<<<256, 512, 0, stream>>>(gWhh, gx, gbhh, outh, hx);
  k_cls<<<TT, 256, 0, stream>>>(outh, clsW, clsb, out);
}

// Round 20
// 407.734 us; speedup vs baseline: 1.1769x; 1.0294x over previous
//
#include <hip/hip_runtime.h>
#include <math.h>

// Problem constants
constexpr int CVOC = 100;
constexpr int NCLS = 18;
constexpr int EE   = 512;   // word emb
constexpr int HHm  = 512;   // main GRU hidden
constexpr int CEc  = 128;   // char emb
constexpr int CHc  = 256;   // char GRU hidden
constexpr int BB   = 64;
constexpr int TT   = 64;
constexpr int CCh  = 16;    // chars per word
constexpr int NTOK = BB*TT;       // 4096
constexpr int G3C  = 3*CHc;       // 768
constexpr int G3H  = 3*HHm;       // 1536
constexpr int KIN  = EE + CHc;    // 768

typedef __attribute__((ext_vector_type(8))) short bf16x8;
typedef __attribute__((ext_vector_type(4))) float f32x4;

__device__ __forceinline__ float sigmoidf_(float x){ return 1.0f/(1.0f + __expf(-x)); }
__device__ __forceinline__ float tanhf_(float x){ return 1.0f - 2.0f/(__expf(2.0f*x) + 1.0f); }
__device__ __forceinline__ unsigned short f2bf(float x){
  unsigned int u = __float_as_uint(x);
  unsigned int r = (u + 0x7FFFu + ((u>>16)&1u)) >> 16;
  return (unsigned short)r;
}

// ---------------------------------------------------------------------------
// K1: char input-projection table, PADDED layout U2p[char][col][4]:
// slot = {r, z, n, pad}; biases folded (+bhh for r,z). One float4/word-col.
__global__ void k_uchar(const float* __restrict__ cemb, const float* __restrict__ wih,
                        const float* __restrict__ bih, const float* __restrict__ bhh,
                        float* __restrict__ U2p){
  const int c = blockIdx.x;        // char 0..99
  const int g = threadIdx.x;       // 0..767
  const float* a = cemb + (size_t)c*CEc;
  const float* w = wih  + (size_t)g*CEc;
  float s = 0.f;
  for(int k=0;k<CEc;k++) s = fmaf(a[k], w[k], s);
  s += bih[g];
  if(g < 2*CHc) s += bhh[g];
  const int gate = g >> 8;
  const int col  = g & 255;
  U2p[((size_t)c*256 + col)*4 + gate] = s;
}

// ---------------------------------------------------------------------------
// f32 -> bf16 (RNE)
__global__ void k_w2bf(const float* __restrict__ in, unsigned short* __restrict__ out,
                       int n){
  int i = blockIdx.x*256 + threadIdx.x;
  if(i < n) out[i] = f2bf(in[i]);
}

// ---------------------------------------------------------------------------
// K2 v9: char GRU, bf16 MFMA; U2 via coalesced float4 loads (round-16 code).
__global__ __launch_bounds__(1024, 1) void k_chargru(
    const int* __restrict__ chars, const float* __restrict__ U2p,
    const unsigned short* __restrict__ Wb, const float* __restrict__ bhh,
    float* __restrict__ char_h){
  __shared__ unsigned short hb[16][280];   // 9KB bf16 h
  __shared__ int chs_all[16][16];          // 1KB [w][t]
  const int tid  = threadIdx.x;
  const int lane = tid & 63;
  const int wv   = tid >> 6;        // 0..15
  const int la   = lane & 15;
  const int lb   = lane >> 4;       // 0..3
  const int w0   = blockIdx.x * 16;
  const int c    = wv*16 + la;      // this thread's h-column (0..255)
  bf16x8 wreg[2][8];
  #pragma unroll
  for(int g=0; g<2; g++){
    const int gcol = g*CHc + c;
    #pragma unroll
    for(int ks=0; ks<8; ks++)
      wreg[g][ks] = *reinterpret_cast<const bf16x8*>(
          &Wb[(size_t)gcol*CHc + ks*32 + lb*8]);
  }
  const unsigned short* wnp = &Wb[(size_t)(2*CHc + c)*CHc + lb*8];  // n-gate row
  const float bhn = bhh[2*CHc + c];
  float hfr[4];
  #pragma unroll
  for(int i=0;i<4;i++) hfr[i]=0.f;
  for(int f=tid; f<16*280; f+=1024) (&hb[0][0])[f] = 0;
  if(tid < 256) chs_all[tid>>4][tid&15] = chars[(size_t)(w0 + (tid>>4))*CCh + (tid&15)];
  __syncthreads();

  for(int t=0; t<CCh; t++){
    float4 u2v[4];
    #pragma unroll
    for(int i=0;i<4;i++){
      const int ch = chs_all[lb*4 + i][t];
      u2v[i] = *reinterpret_cast<const float4*>(&U2p[(((size_t)ch*256) + c)*4]);
    }
    f32x4 acc[3];
    #pragma unroll
    for(int g=0;g<3;g++) acc[g] = (f32x4){0.f,0.f,0.f,0.f};
    {
      bf16x8 wn[4];
      #pragma unroll
      for(int q=0;q<4;q++)
        wn[q] = *reinterpret_cast<const bf16x8*>(wnp + q*32);
      #pragma unroll
      for(int ks=0; ks<4; ks++){
        bf16x8 a = *reinterpret_cast<const bf16x8*>(&hb[la][ks*32 + lb*8]);
        acc[0] = __builtin_amdgcn_mfma_f32_16x16x32_bf16(a, wreg[0][ks], acc[0], 0,0,0);
        acc[1] = __builtin_amdgcn_mfma_f32_16x16x32_bf16(a, wreg[1][ks], acc[1], 0,0,0);
        acc[2] = __builtin_amdgcn_mfma_f32_16x16x32_bf16(a, wn[ks],      acc[2], 0,0,0);
      }
      #pragma unroll
      for(int q=0;q<4;q++)
        wn[q] = *reinterpret_cast<const bf16x8*>(wnp + (4+q)*32);
      #pragma unroll
      for(int ks=4; ks<8; ks++){
        bf16x8 a = *reinterpret_cast<const bf16x8*>(&hb[la][ks*32 + lb*8]);
        acc[0] = __builtin_amdgcn_mfma_f32_16x16x32_bf16(a, wreg[0][ks], acc[0], 0,0,0);
        acc[1] = __builtin_amdgcn_mfma_f32_16x16x32_bf16(a, wreg[1][ks], acc[1], 0,0,0);
        acc[2] = __builtin_amdgcn_mfma_f32_16x16x32_bf16(a, wn[ks-4],    acc[2], 0,0,0);
      }
    }
    __syncthreads();
    #pragma unroll
    for(int i=0;i<4;i++){
      const int w = lb*4 + i;
      float r = sigmoidf_(u2v[i].x + acc[0][i]);
      float z = sigmoidf_(u2v[i].y + acc[1][i]);
      float n = tanhf_   (u2v[i].z + r*(acc[2][i] + bhn));
      float hn = (1.f - z)*n + z*hfr[i];
      hfr[i] = hn;
      hb[w][c] = f2bf(hn);
    }
    __syncthreads();
  }
  #pragma unroll
  for(int i=0;i<4;i++){
    const int w = lb*4 + i;
    char_h[(size_t)(w0+w)*CHc + c] = hfr[i];
  }
}

// ---------------------------------------------------------------------------
// K3: gx GEMM via bf16 MFMA, FUSED gather+pack (round-18 code).
__global__ __launch_bounds__(256) void k_gxmfma(
    const int* __restrict__ x, const float* __restrict__ wemb,
    const float* __restrict__ chh, const unsigned short* __restrict__ Wbih,
    const float* __restrict__ bih, const float* __restrict__ bhh,
    float* __restrict__ gx){
  __shared__ unsigned short As[64][136];   // 17.4KB
  __shared__ int xs[64];
  const int tid  = threadIdx.x;
  const int lane = tid & 63;
  const int wv   = tid >> 6;        // 0..3
  const int la   = lane & 15;
  const int lb   = lane >> 4;       // 0..3
  const int rb   = blockIdx.x * 64;
  const int nb   = blockIdx.y * 64;
  const int g    = nb + wv*16 + la;
  if(tid < 64) xs[tid] = x[rb + tid];
  f32x4 acc[4];
  #pragma unroll
  for(int mt=0;mt<4;mt++) acc[mt] = (f32x4){0.f,0.f,0.f,0.f};
  __syncthreads();
  for(int kc=0; kc<6; kc++){
    #pragma unroll
    for(int i=0;i<4;i++){
      int idx = i*256 + tid;
      int row = idx >> 4, ck = idx & 15;
      int k = kc*128 + ck*8;
      const float* src = (k < EE) ? &wemb[(size_t)xs[row]*EE + k]
                                  : &chh[(size_t)(rb+row)*CHc + (k - EE)];
      float4 v0 = *reinterpret_cast<const float4*>(src);
      float4 v1 = *reinterpret_cast<const float4*>(src + 4);
      unsigned short tmp[8];
      tmp[0]=f2bf(v0.x); tmp[1]=f2bf(v0.y); tmp[2]=f2bf(v0.z); tmp[3]=f2bf(v0.w);
      tmp[4]=f2bf(v1.x); tmp[5]=f2bf(v1.y); tmp[6]=f2bf(v1.z); tmp[7]=f2bf(v1.w);
      *reinterpret_cast<uint4*>(&As[row][ck*8]) = *reinterpret_cast<const uint4*>(tmp);
    }
    __syncthreads();
    #pragma unroll
    for(int ks=0; ks<4; ks++){
      bf16x8 b = *reinterpret_cast<const bf16x8*>(
          &Wbih[(size_t)g*KIN + kc*128 + ks*32 + lb*8]);
      #pragma unroll
      for(int mt=0;mt<4;mt++){
        bf16x8 a = *reinterpret_cast<const bf16x8*>(&As[mt*16 + la][ks*32 + lb*8]);
        acc[mt] = __builtin_amdgcn_mfma_f32_16x16x32_bf16(a, b, acc[mt], 0,0,0);
      }
    }
    __syncthreads();
  }
  const float bias = bih[g] + (g < 2*HHm ? bhh[g] : 0.f);
  #pragma unroll
  for(int mt=0;mt<4;mt++)
    #pragma unroll
    for(int i=0;i<4;i++){
      int row = rb + mt*16 + lb*4 + i;
      gx[(size_t)row*G3H + g] = acc[mt][i] + bias;
    }
}

// ---------------------------------------------------------------------------
// K4 v11: main GRU, packed exchange + WAVE-LOCAL staging (decoupled waves).
// Wave kw polls/stages ONLY its own k-window: 8 rows x 32 packed u64 covering
// j in [kw*64, +64) -> dot starts when ITS 4 producer blocks are done (was:
// barrier on all 32). Stage->dot barrier eliminated (wave-local LDS, compiler
// lgkmcnt-ordered). 2 barriers/step: red-write->finalize, finalize->next
// (trailing one protects red from a fast peer's next-step overwrite).
// Rest identical to v10 (hreg h_old, packed bf16-pair hx, XCD-local bb).
__global__ __launch_bounds__(512) void k_grumain(
    const float* __restrict__ Whh, const float* __restrict__ gx,
    const float* __restrict__ bhh, float* __restrict__ outh,
    unsigned long long* __restrict__ hx){
  __shared__ float hsh[8][516];      // 16.5KB
  __shared__ float red[3][8][16][9]; // 13.8KB
  const int tid  = threadIdx.x;
  const int lane = tid & 63;
  const int kw   = tid >> 6;
  const int jp   = lane & 15;
  const int bq   = lane >> 4;
  const int jb   = blockIdx.x >> 3;   // 0..31
  const int bb   = blockIdx.x & 7;    // XCD-local batch slice
  const int jglob = jb*16 + jp;
  const int kbase = kw*64 + bq*16;
  float4 wreg[3][4];
  #pragma unroll
  for(int g=0; g<3; g++)
    #pragma unroll
    for(int q=0; q<4; q++)
      wreg[g][q] = *reinterpret_cast<const float4*>(
          &Whh[((size_t)g*HHm + jglob)*HHm + kbase + q*4]);
  const int fb  = tid >> 4;
  const int fj  = tid & 15;
  const int fjg = jb*16 + fj;
  const int fbg = bb*8 + fb;
  const float fbhn = bhh[2*HHm + fjg];
  float hreg = 0.f;                  // persistent f32 h_old (exact z-path)

  for(int t=0; t<TT; t++){
    float gxr=0.f, gxz=0.f, gxn=0.f;
    if(tid < 128){
      const size_t tok = (size_t)fbg*TT + t;
      gxr = gx[tok*G3H +           fjg];
      gxz = gx[tok*G3H + HHm +     fjg];
      gxn = gx[tok*G3H + 2*HHm +   fjg];
    }
    if(t > 0){
      const unsigned int want = (unsigned int)t;
      const size_t sbase = (size_t)((t-1)&1)*BB*(HHm/2);
      // wave-local poll+stage: 8 rows x 32 packed j2 in [kw*32,+32), 4/lane
      const unsigned long long* p[4];
      unsigned long long v[4];
      #pragma unroll
      for(int i=0;i<4;i++){
        int f = i*64 + lane;          // 0..255 within wave
        int b = f >> 5, jj = f & 31;
        p[i] = &hx[sbase + (size_t)(bb*8+b)*(HHm/2) + kw*32 + jj];
        v[i] = __hip_atomic_load(p[i], __ATOMIC_RELAXED, __HIP_MEMORY_SCOPE_AGENT);
      }
      #pragma unroll
      for(int i=0;i<4;i++){
        while((unsigned int)(v[i]>>32) != want){
          __builtin_amdgcn_s_sleep(1);
          v[i] = __hip_atomic_load(p[i], __ATOMIC_RELAXED, __HIP_MEMORY_SCOPE_AGENT);
        }
        int f = i*64 + lane;
        int b = f >> 5, jj = f & 31;
        unsigned int lo = (unsigned int)v[i];
        hsh[b][kw*64 + jj*2+0] = __uint_as_float((lo & 0xFFFFu) << 16);
        hsh[b][kw*64 + jj*2+1] = __uint_as_float((lo & 0xFFFF0000u));
      }
      // NO barrier: dot reads only this wave's staged window
      float aR[8], aZ[8], aN[8];
      #pragma unroll
      for(int b=0;b<8;b++){ aR[b]=0.f; aZ[b]=0.f; aN[b]=0.f; }
      #pragma unroll
      for(int b=0; b<8; b++){
        float4 h0 = *reinterpret_cast<const float4*>(&hsh[b][kbase+0]);
        float4 h1 = *reinterpret_cast<const float4*>(&hsh[b][kbase+4]);
        float4 h2 = *reinterpret_cast<const float4*>(&hsh[b][kbase+8]);
        float4 h3 = *reinterpret_cast<const float4*>(&hsh[b][kbase+12]);
        aR[b] = fmaf(h0.x,wreg[0][0].x, fmaf(h0.y,wreg[0][0].y, fmaf(h0.z,wreg[0][0].z, fmaf(h0.w,wreg[0][0].w, aR[b]))));
        aR[b] = fmaf(h1.x,wreg[0][1].x, fmaf(h1.y,wreg[0][1].y, fmaf(h1.z,wreg[0][1].z, fmaf(h1.w,wreg[0][1].w, aR[b]))));
        aR[b] = fmaf(h2.x,wreg[0][2].x, fmaf(h2.y,wreg[0][2].y, fmaf(h2.z,wreg[0][2].z, fmaf(h2.w,wreg[0][2].w, aR[b]))));
        aR[b] = fmaf(h3.x,wreg[0][3].x, fmaf(h3.y,wreg[0][3].y, fmaf(h3.z,wreg[0][3].z, fmaf(h3.w,wreg[0][3].w, aR[b]))));
        aZ[b] = fmaf(h0.x,wreg[1][0].x, fmaf(h0.y,wreg[1][0].y, fmaf(h0.z,wreg[1][0].z, fmaf(h0.w,wreg[1][0].w, aZ[b]))));
        aZ[b] = fmaf(h1.x,wreg[1][1].x, fmaf(h1.y,wreg[1][1].y, fmaf(h1.z,wreg[1][1].z, fmaf(h1.w,wreg[1][1].w, aZ[b]))));
        aZ[b] = fmaf(h2.x,wreg[1][2].x, fmaf(h2.y,wreg[1][2].y, fmaf(h2.z,wreg[1][2].z, fmaf(h2.w,wreg[1][2].w, aZ[b]))));
        aZ[b] = fmaf(h3.x,wreg[1][3].x, fmaf(h3.y,wreg[1][3].y, fmaf(h3.z,wreg[1][3].z, fmaf(h3.w,wreg[1][3].w, aZ[b]))));
        aN[b] = fmaf(h0.x,wreg[2][0].x, fmaf(h0.y,wreg[2][0].y, fmaf(h0.z,wreg[2][0].z, fmaf(h0.w,wreg[2][0].w, aN[b]))));
        aN[b] = fmaf(h1.x,wreg[2][1].x, fmaf(h1.y,wreg[2][1].y, fmaf(h1.z,wreg[2][1].z, fmaf(h1.w,wreg[2][1].w, aN[b]))));
        aN[b] = fmaf(h2.x,wreg[2][2].x, fmaf(h2.y,wreg[2][2].y, fmaf(h2.z,wreg[2][2].z, fmaf(h2.w,wreg[2][2].w, aN[b]))));
        aN[b] = fmaf(h3.x,wreg[2][3].x, fmaf(h3.y,wreg[2][3].y, fmaf(h3.z,wreg[2][3].z, fmaf(h3.w,wreg[2][3].w, aN[b]))));
      }
      #pragma unroll
      for(int b=0;b<8;b++){
        aR[b] += __shfl_xor(aR[b], 16, 64); aR[b] += __shfl_xor(aR[b], 32, 64);
        aZ[b] += __shfl_xor(aZ[b], 16, 64); aZ[b] += __shfl_xor(aZ[b], 32, 64);
        aN[b] += __shfl_xor(aN[b], 16, 64); aN[b] += __shfl_xor(aN[b], 32, 64);
      }
      #pragma unroll
      for(int i=0;i<2;i++){
        int b = bq*2 + i;
        red[0][b][jp][kw] = aR[b];
        red[1][b][jp][kw] = aZ[b];
        red[2][b][jp][kw] = aN[b];
      }
      __syncthreads();
    }
    if(tid < 128){
      float sR=0.f, sZ=0.f, sN=0.f;
      if(t > 0){
        #pragma unroll
        for(int w=0; w<8; w++){
          sR += red[0][fb][fj][w];
          sZ += red[1][fb][fj][w];
          sN += red[2][fb][fj][w];
        }
      }
      float rg = sigmoidf_(gxr + sR);
      float zg = sigmoidf_(gxz + sZ);
      float ng = tanhf_   (gxn + rg*(sN + fbhn));
      float hnew = (1.f - zg)*ng + zg*hreg;     // exact f32 h_old
      hreg = hnew;
      outh[((size_t)t*BB + fbg)*HHm + fjg] = hnew;   // f32 for k_cls
      unsigned int mybf = (unsigned int)f2bf(hnew);
      unsigned int nbbf = (unsigned int)__shfl_xor((int)mybf, 1, 64);
      if((fj & 1) == 0){
        unsigned int lo = mybf | (nbbf << 16);
        unsigned long long pv = ((unsigned long long)(unsigned int)(t+1) << 32)
                                | (unsigned long long)lo;
        __hip_atomic_store(&hx[(size_t)(t&1)*BB*(HHm/2) + (size_t)fbg*(HHm/2) + (fjg>>1)],
                           pv, __ATOMIC_RELAXED, __HIP_MEMORY_SCOPE_AGENT);
      }
    }
    __syncthreads();   // protect red from a fast peer's next-step overwrite
  }
}

// ---------------------------------------------------------------------------
// K5: classifier. One block per time-step t; reads outh[t][b][j].
__global__ __launch_bounds__(256) void k_cls(
    const float* __restrict__ outh, const float* __restrict__ clsW,
    const float* __restrict__ clsb, float* __restrict__ out){
  __shared__ float wls[20*HHm];     // 40KB
  __shared__ float hch[64][129];    // 33KB
  const int tid = threadIdx.x;
  const int t = blockIdx.x;
  const int b = tid & 63;
  const int q = tid >> 6;
  const int c0 = q*5;
  for(int f = tid*4; f < 20*HHm; f += 1024){
    float4 v = make_float4(0.f,0.f,0.f,0.f);
    if(f < NCLS*HHm) v = *reinterpret_cast<const float4*>(&clsW[f]);
    *reinterpret_cast<float4*>(&wls[f]) = v;
  }
  float acc[5] = {0.f,0.f,0.f,0.f,0.f};
  for(int kc=0; kc<4; kc++){
    __syncthreads();
    for(int i=0;i<32;i++){
      int f = i*256 + tid;
      int b2 = f >> 7, kk = f & 127;
      hch[b2][kk] = outh[((size_t)t*BB + b2)*HHm + kc*128 + kk];
    }
    __syncthreads();
    for(int k=0;k<128;k++){
      float hv = hch[b][k];
      #pragma unroll
      for(int i=0;i<5;i++)
        acc[i] = fmaf(hv, wls[(size_t)(c0+i)*HHm + kc*128 + k], acc[i]);
    }
  }
  #pragma unroll
  for(int i=0;i<5;i++){
    int cls = c0 + i;
    if(cls < NCLS) out[((size_t)b*TT + t)*NCLS + cls] = acc[i] + clsb[cls];
  }
}

// ---------------------------------------------------------------------------
extern "C" void kernel_launch(void* const* d_in, const int* in_sizes, int n_in,
                              void* d_out, int out_size, void* d_ws, size_t ws_size,
                              hipStream_t stream){
  const int*   x     = (const int*)d_in[0];
  const int*   chars = (const int*)d_in[1];
  const float* wemb  = (const float*)d_in[2];
  const float* cemb  = (const float*)d_in[3];
  const float* cWih  = (const float*)d_in[4];
  const float* cWhh  = (const float*)d_in[5];
  const float* cbih  = (const float*)d_in[6];
  const float* cbhh  = (const float*)d_in[7];
  const float* gWih  = (const float*)d_in[8];
  const float* gWhh  = (const float*)d_in[9];
  const float* gbih  = (const float*)d_in[10];
  const float* gbhh  = (const float*)d_in[11];
  const float* clsW  = (const float*)d_in[12];
  const float* clsb  = (const float*)d_in[13];
  float* out = (float*)d_out;
  float* ws  = (float*)d_ws;

  // workspace layout (floats unless noted)
  float* U2p   = ws;                   // 100*256*4  = 102400
  float* chh   = U2p + 102400;         // 4096*256   = 1048576
  float* gx    = chh + 1048576;        // 4096*1536  = 6291456   [token][g]
  float* outh  = gx + 6291456;         // 64*64*512  = 2097152   [t][b][j]
  unsigned long long* hx = (unsigned long long*)(outh + 2097152); // 2*64*256 u64 (packed)
  unsigned short* Wb   = (unsigned short*)(hx + 2*BB*(HHm/2)); // 768*256 bf16 (char Whh)
  unsigned short* Wbih = Wb + G3C*CHc;                         // 1536*768 bf16 (gWih)

  k_uchar<<<CVOC, G3C, 0, stream>>>(cemb, cWih, cbih, cbhh, U2p);
  k_w2bf<<<(G3C*CHc + 255)/256, 256, 0, stream>>>(cWhh, Wb, G3C*CHc);
  k_w2bf<<<(G3H*KIN + 255)/256, 256, 0, stream>>>(gWih, Wbih, G3H*KIN);
  k_chargru<<<NTOK/16, 1024, 0, stream>>>(chars, U2p, Wb, cbhh, chh);
  k_gxmfma<<<dim3(NTOK/64, G3H/64), 256, 0, stream>>>(x, wemb, chh, Wbih, gbih, gbhh, gx);
  k_grumain<<<256, 512, 0, stream>>>(gWhh, gx, gbhh, outh, hx);
  k_cls<<<TT, 256, 0, stream>>>(outh, clsW, clsb, out);
}